// Round 4
// baseline (122.441 us; speedup 1.0000x reference)
//
#include <hip/hip_runtime.h>
#include <cstdint>
#include <cstddef>

#define B_ 8
#define C_ 10
#define HW_ 65536
#define NPIX_ (B_ * HW_)
#define NB_ 1024

// ---------- packed float2 helpers (SLP-friendly: x/y ops adjacent) ----------
__device__ __forceinline__ float2 mk2(float a, float b) { float2 r; r.x = a; r.y = b; return r; }
__device__ __forceinline__ float2 bc2(float a) { return mk2(a, a); }
__device__ __forceinline__ float2 add2(float2 a, float2 b) { return mk2(a.x + b.x, a.y + b.y); }
__device__ __forceinline__ float2 sub2(float2 a, float2 b) { return mk2(a.x - b.x, a.y - b.y); }
__device__ __forceinline__ float2 mul2(float2 a, float2 b) { return mk2(a.x * b.x, a.y * b.y); }
__device__ __forceinline__ float2 fma2(float2 a, float2 b, float2 c) {
    return mk2(fmaf(a.x, b.x, c.x), fmaf(a.y, b.y, c.y));
}
__device__ __forceinline__ float2 max2(float2 a, float2 b) { return mk2(fmaxf(a.x, b.x), fmaxf(a.y, b.y)); }
__device__ __forceinline__ float2 min2(float2 a, float2 b) { return mk2(fminf(a.x, b.x), fminf(a.y, b.y)); }
__device__ __forceinline__ float2 abs2(float2 a) { return mk2(fabsf(a.x), fabsf(a.y)); }
__device__ __forceinline__ float2 neg2(float2 a) { return mk2(-a.x, -a.y); }
__device__ __forceinline__ float2 div2(float2 a, float2 b) {
    return mk2(__fdividef(a.x, b.x), __fdividef(a.y, b.y));
}
__device__ __forceinline__ float2 expf2(float2 a) { return mk2(__expf(a.x), __expf(a.y)); }
__device__ __forceinline__ float2 logf2(float2 a) { return mk2(__logf(a.x), __logf(a.y)); }
__device__ __forceinline__ float sgnf(float v) { return (v > 0.f) ? 1.f : ((v < 0.f) ? -1.f : 0.f); }
__device__ __forceinline__ float2 sl12(float2 p, float2 t) {
    float2 d = abs2(sub2(p, t));
    float rx = (d.x < 1.f) ? 0.5f * d.x * d.x : d.x - 0.5f;
    float ry = (d.y < 1.f) ? 0.5f * d.y * d.y : d.y - 0.5f;
    return mk2(rx, ry);
}

__global__ __launch_bounds__(256, 3) void bev_loss_main(
    const float* __restrict__ cls_pred, const float* __restrict__ reg_pred,
    const float* __restrict__ iou_pred, const int* __restrict__ cls_tg,
    const float* __restrict__ reg_tg, const float* __restrict__ reg_w,
    const float* __restrict__ iou_tg, double* __restrict__ part,
    unsigned int* __restrict__ ticket, float* __restrict__ out)
{
    int t  = blockIdx.x * blockDim.x + threadIdx.x;   // 0 .. 262143
    int n0 = t << 1;
    int b  = n0 >> 16;
    int hw = n0 & 65535;

    // ---------------- vectorized loads (2 pixels per thread) ----------------
    float2 lg[C_];
    {
        const float* cp = cls_pred + (size_t)b * C_ * HW_ + hw;
        #pragma unroll
        for (int c = 0; c < C_; c++)
            lg[c] = *reinterpret_cast<const float2*>(cp + (size_t)c * HW_);
    }
    float2 P[9], T[9];
    {
        const float* rp = reg_pred + (size_t)b * 9 * HW_ + hw;
        const float* rt = reg_tg  + (size_t)b * 9 * HW_ + hw;
        #pragma unroll
        for (int k = 0; k < 9; k++) {
            P[k] = *reinterpret_cast<const float2*>(rp + (size_t)k * HW_);
            T[k] = *reinterpret_cast<const float2*>(rt + (size_t)k * HW_);
        }
    }
    int2   ct2 = *reinterpret_cast<const int2*>(cls_tg + n0);
    float2 w2  = *reinterpret_cast<const float2*>(reg_w + n0);
    float2 xi  = *reinterpret_cast<const float2*>(iou_pred + n0);
    float2 yi  = *reinterpret_cast<const float2*>(iou_tg + n0);

    // ---------------- focal loss (packed, per-component selects) ----------------
    float2 o0;
    {
        float2 m = lg[0];
        #pragma unroll
        for (int c = 1; c < C_; c++) m = max2(m, lg[c]);
        int tlx = ct2.x < 0 ? 0 : (ct2.x > C_ - 1 ? C_ - 1 : ct2.x);
        int tly = ct2.y < 0 ? 0 : (ct2.y > C_ - 1 ? C_ - 1 : ct2.y);
        float2 se = bc2(0.f), et = bc2(0.f);
        #pragma unroll
        for (int c = 0; c < C_; c++) {
            float2 e = expf2(sub2(lg[c], m));
            se = add2(se, e);
            et.x = (c == tlx) ? e.x : et.x;
            et.y = (c == tly) ? e.y : et.y;
        }
        float2 pt = div2(et, se);
        pt = min2(max2(pt, bc2(1e-7f)), bc2(1.0f - 1e-7f));
        float2 at = mk2(ct2.x > 0 ? 0.25f : 0.75f, ct2.y > 0 ? 0.25f : 0.75f);
        float2 omp = sub2(bc2(1.f), pt);
        float2 fl = mul2(neg2(at), mul2(mul2(omp, omp), logf2(pt)));
        o0 = mk2(ct2.x >= 0 ? fl.x : 0.f, ct2.y >= 0 ? fl.y : 0.f);
    }

    float2 pos = mk2(w2.x > 0.f ? 1.f : 0.f, w2.y > 0.f ? 1.f : 0.f);

    // ---------------- corners (packed) ----------------
    float2 Ax[4], Ay[4], Bx[4], By[4];
    {
        const float sbx[4] = { 1.f, -1.f, -1.f, 1.f };
        const float sby[4] = { -1.f, -1.f, 1.f, 1.f };
        float ssx, ccx, ssy, ccy;
        __sincosf(P[6].x, &ssx, &ccx); __sincosf(P[6].y, &ssy, &ccy);
        float2 ss = mk2(ssx, ssy), cc = mk2(ccx, ccy);
        float2 hx = mul2(bc2(0.5f), P[3]), hy = mul2(bc2(0.5f), P[4]);
        #pragma unroll
        for (int i = 0; i < 4; i++) {
            float2 px = mul2(bc2(sbx[i]), hx), py = mul2(bc2(sby[i]), hy);
            Ax[i] = add2(sub2(mul2(px, cc), mul2(py, ss)), P[0]);
            Ay[i] = add2(fma2(px, ss, mul2(py, cc)), P[1]);
        }
        __sincosf(T[6].x, &ssx, &ccx); __sincosf(T[6].y, &ssy, &ccy);
        ss = mk2(ssx, ssy); cc = mk2(ccx, ccy);
        hx = mul2(bc2(0.5f), T[3]); hy = mul2(bc2(0.5f), T[4]);
        #pragma unroll
        for (int i = 0; i < 4; i++) {
            float2 px = mul2(bc2(sbx[i]), hx), py = mul2(bc2(sby[i]), hy);
            Bx[i] = add2(sub2(mul2(px, cc), mul2(py, ss)), T[0]);
            By[i] = add2(fma2(px, ss, mul2(py, cc)), T[1]);
        }
    }

    // ---------------- signed areas + orientation signs ----------------
    float2 sa = bc2(0.f), sb = bc2(0.f);
    #pragma unroll
    for (int i = 0; i < 4; i++) {
        int j = (i + 1) & 3;
        sa = add2(sa, sub2(mul2(Ax[i], Ay[j]), mul2(Ay[i], Ax[j])));
        sb = add2(sb, sub2(mul2(Bx[i], By[j]), mul2(By[i], Bx[j])));
    }
    sa = mul2(bc2(0.5f), sa); sb = mul2(bc2(0.5f), sb);
    float2 sgnA = mk2(sgnf(sa.x), sgnf(sa.y));
    float2 sgnB = mk2(sgnf(sb.x), sgnf(sb.y));

    // ---------------- rotated IoU: Green's-theorem clip (packed) ----------------
    float2 S = bc2(0.f);
    {
        float2 dB[4][4];
        #pragma unroll
        for (int j = 0; j < 4; j++) {
            int j1 = (j + 1) & 3;
            float2 sx = mul2(sgnB, sub2(Bx[j1], Bx[j]));
            float2 sy = mul2(sgnB, sub2(By[j1], By[j]));
            float2 kj = sub2(mul2(sx, By[j]), mul2(sy, Bx[j]));
            #pragma unroll
            for (int i = 0; i < 4; i++)
                dB[j][i] = sub2(sub2(mul2(sx, Ay[i]), mul2(sy, Ax[i])), kj);
        }
        #pragma unroll
        for (int i = 0; i < 4; i++) {
            int i1 = (i + 1) & 3;
            float2 t0 = bc2(0.f), t1 = bc2(1.f);
            #pragma unroll
            for (int j = 0; j < 4; j++) {
                float2 d0 = dB[j][i], d1 = dB[j][i1];
                float2 den = sub2(d1, d0);
                float2 tt = div2(neg2(d0), den);
                float e0x = (den.x > 0.f) ? tt.x : ((den.x == 0.f && d0.x < 0.f) ? 2.f : 0.f);
                float e0y = (den.y > 0.f) ? tt.y : ((den.y == 0.f && d0.y < 0.f) ? 2.f : 0.f);
                t0 = max2(t0, mk2(e0x, e0y));
                float e1x = (den.x < 0.f) ? tt.x : 1.f;
                float e1y = (den.y < 0.f) ? tt.y : 1.f;
                t1 = min2(t1, mk2(e1x, e1y));
            }
            float2 cr = sub2(mul2(Ax[i], Ay[i1]), mul2(Ay[i], Ax[i1]));
            S = add2(S, mul2(cr, max2(sub2(t1, t0), bc2(0.f))));
        }
    }
    {
        float2 dA[4][4];
        #pragma unroll
        for (int j = 0; j < 4; j++) {
            int j1 = (j + 1) & 3;
            float2 sx = mul2(sgnA, sub2(Ax[j1], Ax[j]));
            float2 sy = mul2(sgnA, sub2(Ay[j1], Ay[j]));
            float2 kj = sub2(mul2(sx, Ay[j]), mul2(sy, Ax[j]));
            #pragma unroll
            for (int i = 0; i < 4; i++)
                dA[j][i] = sub2(sub2(mul2(sx, By[i]), mul2(sy, Bx[i])), kj);
        }
        #pragma unroll
        for (int i = 0; i < 4; i++) {
            int i1 = (i + 1) & 3;
            float2 t0 = bc2(0.f), t1 = bc2(1.f);
            #pragma unroll
            for (int j = 0; j < 4; j++) {
                float2 d0 = dA[j][i], d1 = dA[j][i1];
                float2 den = sub2(d1, d0);
                float2 tt = div2(neg2(d0), den);
                float e0x = (den.x > 0.f) ? tt.x : ((den.x == 0.f && d0.x < 0.f) ? 2.f : 0.f);
                float e0y = (den.y > 0.f) ? tt.y : ((den.y == 0.f && d0.y < 0.f) ? 2.f : 0.f);
                t0 = max2(t0, mk2(e0x, e0y));
                float e1x = (den.x < 0.f) ? tt.x : 1.f;
                float e1y = (den.y < 0.f) ? tt.y : 1.f;
                t1 = min2(t1, mk2(e1x, e1y));
            }
            float2 cr = sub2(mul2(Bx[i], By[i1]), mul2(By[i], Bx[i1]));
            S = add2(S, mul2(cr, max2(sub2(t1, t0), bc2(0.f))));
        }
    }
    float2 inter = mul2(bc2(0.5f), abs2(S));
    float2 areaA = abs2(sa), areaB = abs2(sb);
    float2 uni = sub2(add2(areaA, areaB), inter);
    float2 iou;
    iou.x = (uni.x > 1e-7f) ? __fdividef(inter.x, uni.x) : 0.f;
    iou.y = (uni.y > 1e-7f) ? __fdividef(inter.y, uni.y) : 0.f;

    // ---------------- DIoU-style bev loss (packed) ----------------
    float2 o1;
    {
        float2 ddx = sub2(P[0], T[0]), ddy = sub2(P[1], T[1]);
        float2 d2v = fma2(ddx, ddx, mul2(ddy, ddy));
        float2 mnx = Ax[0], mxx = Ax[0], mny = Ay[0], mxy = Ay[0];
        #pragma unroll
        for (int i = 1; i < 4; i++) {
            mnx = min2(mnx, Ax[i]); mxx = max2(mxx, Ax[i]);
            mny = min2(mny, Ay[i]); mxy = max2(mxy, Ay[i]);
        }
        #pragma unroll
        for (int i = 0; i < 4; i++) {
            mnx = min2(mnx, Bx[i]); mxx = max2(mxx, Bx[i]);
            mny = min2(mny, By[i]); mxy = max2(mxy, By[i]);
        }
        float2 exd = sub2(mxx, mnx), eyd = sub2(mxy, mny);
        float2 c2v = max2(fma2(exd, exd, mul2(eyd, eyd)), bc2(1e-7f));
        float2 atp = mk2(atanf(__fdividef(P[4].x, fmaxf(P[3].x, 1e-7f))),
                         atanf(__fdividef(P[4].y, fmaxf(P[3].y, 1e-7f))));
        float2 att = mk2(atanf(__fdividef(T[4].x, fmaxf(T[3].x, 1e-7f))),
                         atanf(__fdividef(T[4].y, fmaxf(T[3].y, 1e-7f))));
        float2 dv = sub2(atp, att);
        float2 vv = mul2(bc2(0.4052847345693511f), mul2(dv, dv));
        float2 dn = add2(add2(sub2(bc2(1.f), iou), vv), bc2(1e-7f));
        float2 alpha_c = div2(vv, dn);
        float2 lbev = add2(add2(sub2(bc2(1.f), iou), div2(d2v, c2v)), mul2(alpha_c, vv));
        o1 = mul2(lbev, pos);
    }

    // ---------------- smooth-L1 z / h / vel + BCE ----------------
    float2 o2 = mul2(sl12(P[2], T[2]), pos);
    float2 o3 = mul2(sl12(P[5], T[5]), pos);
    float2 o4 = mul2(add2(sl12(P[7], T[7]), sl12(P[8], T[8])), pos);
    float2 bce = add2(sub2(max2(xi, bc2(0.f)), mul2(xi, yi)),
                      logf2(add2(bc2(1.f), expf2(neg2(abs2(xi))))));
    float2 o5 = mul2(bce, pos);

    // ---------------- block reduction ----------------
    double a[7] = {
        (double)o0.x + (double)o0.y, (double)o1.x + (double)o1.y,
        (double)o2.x + (double)o2.y, (double)o3.x + (double)o3.y,
        (double)o4.x + (double)o4.y, (double)o5.x + (double)o5.y,
        (double)pos.x + (double)pos.y
    };
    __shared__ double red[7][4];
    __shared__ bool lastf;
    int lane = threadIdx.x & 63;
    int wv   = threadIdx.x >> 6;
    #pragma unroll
    for (int k = 0; k < 7; k++) {
        double s = a[k];
        for (int off = 32; off > 0; off >>= 1) s += __shfl_down(s, off, 64);
        if (lane == 0) red[k][wv] = s;
    }
    __syncthreads();
    if (threadIdx.x == 0) {
        #pragma unroll
        for (int k = 0; k < 7; k++)
            part[(size_t)k * NB_ + blockIdx.x] = red[k][0] + red[k][1] + red[k][2] + red[k][3];
    }
    __threadfence();                       // release partials (device scope)
    if (threadIdx.x == 0) {
        unsigned tk = atomicAdd(ticket, 1u);
        lastf = (tk == NB_ - 1);
    }
    __syncthreads();                       // also makes `red` safe to reuse
    if (!lastf) return;

    // ---------------- final reduction in the last-arriving block ----------------
    __threadfence();                       // acquire partials
    double s[7] = { 0, 0, 0, 0, 0, 0, 0 };
    #pragma unroll
    for (int k = 0; k < 7; k++)
        for (int r = threadIdx.x; r < NB_; r += 256)
            s[k] += part[(size_t)k * NB_ + r];
    #pragma unroll
    for (int k = 0; k < 7; k++) {
        double v = s[k];
        for (int off = 32; off > 0; off >>= 1) v += __shfl_down(v, off, 64);
        if (lane == 0) red[k][wv] = v;
    }
    __syncthreads();
    if (threadIdx.x == 0) {
        double npos = fmax(red[6][0] + red[6][1] + red[6][2] + red[6][3], 1.0);
        #pragma unroll
        for (int k = 0; k < 6; k++)
            out[k] = (float)((red[k][0] + red[k][1] + red[k][2] + red[k][3]) / npos);
    }
}

extern "C" void kernel_launch(void* const* d_in, const int* in_sizes, int n_in,
                              void* d_out, int out_size, void* d_ws, size_t ws_size,
                              hipStream_t stream) {
    const float* cls_pred = (const float*)d_in[0];
    const float* reg_pred = (const float*)d_in[1];
    const float* iou_pred = (const float*)d_in[2];
    const int*   cls_tg   = (const int*)d_in[3];
    const float* reg_tg   = (const float*)d_in[4];
    const float* reg_w    = (const float*)d_in[5];
    const float* iou_tg   = (const float*)d_in[6];
    float* out = (float*)d_out;

    double* part = (double*)d_ws;                              // 7 * 1024 doubles
    unsigned int* ticket = (unsigned int*)((char*)d_ws + (size_t)7 * NB_ * sizeof(double));

    hipMemsetAsync(ticket, 0, sizeof(unsigned int), stream);   // zero the ticket each call

    bev_loss_main<<<NB_, 256, 0, stream>>>(cls_pred, reg_pred, iou_pred, cls_tg,
                                           reg_tg, reg_w, iou_tg, part, ticket, out);
}